// Round 1
// 310.780 us; speedup vs baseline: 1.2834x; 1.2834x over previous
//
#include <hip/hip_runtime.h>
#include <math.h>

// Problem constants
#define NREL 499        // 2*MAX_LEN-1
#define NREL_PAD 500    // row stride for qrel (2000 B, 16-B aligned)
#define LDB 72          // bf16 LDS row stride (flash kernel)

typedef __attribute__((ext_vector_type(8))) short bf16x8;
typedef __attribute__((ext_vector_type(4))) float f32x4;

__device__ __forceinline__ float bf2f(ushort x) {
  union { unsigned u; float f; } v; v.u = ((unsigned)x) << 16; return v.f;
}
__device__ __forceinline__ ushort f2bf(float x) {
  union { float f; unsigned u; } v; v.f = x;
  return (ushort)((v.u + 0x8000u) >> 16);
}
__device__ __forceinline__ bf16x8 pack8(float4 a, float4 b) {
  bf16x8 r;
  r[0] = (short)f2bf(a.x); r[1] = (short)f2bf(a.y);
  r[2] = (short)f2bf(a.z); r[3] = (short)f2bf(a.w);
  r[4] = (short)f2bf(b.x); r[5] = (short)f2bf(b.y);
  r[6] = (short)f2bf(b.z); r[7] = (short)f2bf(b.w);
  return r;
}

// ============================================================================
// prep_wt: Wt[z][n][k] (bf16) = W_z[k][n], z = {q,k,v,o}. Grid (8,8,4).
// ============================================================================
__global__ __launch_bounds__(256) void prep_wt(const float* __restrict__ W0,
                                               const float* __restrict__ W1,
                                               const float* __restrict__ W2,
                                               const float* __restrict__ W3,
                                               ushort* __restrict__ Wt) {
  __shared__ float T[64][68];
  const int t = threadIdx.x;
  const int k0 = blockIdx.x * 64, n0 = blockIdx.y * 64, z = blockIdx.z;
  const float* W = (z == 0) ? W0 : (z == 1) ? W1 : (z == 2) ? W2 : W3;
#pragma unroll
  for (int s = 0; s < 4; ++s) {
    int idx = t + s * 256;
    int r = idx >> 4, c4 = (idx & 15) << 2;
    *(float4*)&T[r][c4] = *(const float4*)(W + (size_t)(k0 + r) * 512 + n0 + c4);
  }
  __syncthreads();
#pragma unroll
  for (int s = 0; s < 4; ++s) {
    int idx = t + s * 256;
    int row = idx >> 4, c4 = (idx & 15) << 2;  // row = n_local, c4 = k_local
    ushort4 u = make_ushort4(f2bf(T[c4 + 0][row]), f2bf(T[c4 + 1][row]),
                             f2bf(T[c4 + 2][row]), f2bf(T[c4 + 3][row]));
    *(ushort4*)(Wt + (size_t)z * 262144 + (size_t)(n0 + row) * 512 + k0 + c4) = u;
  }
}

// ============================================================================
// gemm_body: C[4096x512] = A(fp32) @ Wt^T(bf16 [n][k]) + bias. No LDS; A/W
// fragments straight from global (Wt L2-resident). Tile 64x64, 4 waves.
// MODE 0: fp32 row-major out [4096][512]               (output projection)
// MODE 1: bf16 Vt [bh][64 d][2048 l] (operands swapped -> coalesced stores)
// MODE 2: bf16 row-major head-split [bh][2048 l][64 d] (Q, K)
// ============================================================================
template <int MODE>
__device__ __forceinline__ void gemm_body(const float* __restrict__ A,
                                          const ushort* __restrict__ Wt,
                                          const float* __restrict__ bias,
                                          void* __restrict__ outv,
                                          int bx, int by) {
  const int t = threadIdx.x;
  const int lane = t & 63, wave = t >> 6;
  const int m16 = lane & 15, quad = lane >> 4;
  const int i0 = by * 64;
  const int n0 = bx * 64;
  f32x4 acc[4] = {{0.f, 0.f, 0.f, 0.f}, {0.f, 0.f, 0.f, 0.f},
                  {0.f, 0.f, 0.f, 0.f}, {0.f, 0.f, 0.f, 0.f}};

  if (MODE != 1) {
    // D rows = i (wave strip), cols = n. acc[nt]: n-subtile nt.
    const float* arow = A + (size_t)(i0 + (wave << 4) + m16) * 512 + (quad << 3);
#pragma unroll 4
    for (int kc = 0; kc < 16; ++kc) {
      float4 a0 = *(const float4*)(arow + kc * 32);
      float4 a1 = *(const float4*)(arow + kc * 32 + 4);
      bf16x8 af = pack8(a0, a1);
#pragma unroll
      for (int nt = 0; nt < 4; ++nt) {
        bf16x8 wf = *(const bf16x8*)(Wt + (size_t)(n0 + (nt << 4) + m16) * 512 +
                                     kc * 32 + (quad << 3));
        acc[nt] = __builtin_amdgcn_mfma_f32_16x16x32_bf16(af, wf, acc[nt], 0, 0, 0);
      }
    }
  } else {
    // D rows = n (wave strip), cols = i. acc[it]: i-subtile it.
    const ushort* wrow = Wt + (size_t)(n0 + (wave << 4) + m16) * 512 + (quad << 3);
#pragma unroll 2
    for (int kc = 0; kc < 16; ++kc) {
      bf16x8 wf = *(const bf16x8*)(wrow + kc * 32);
#pragma unroll
      for (int it = 0; it < 4; ++it) {
        const float* ap = A + (size_t)(i0 + (it << 4) + m16) * 512 + kc * 32 + (quad << 3);
        bf16x8 af = pack8(*(const float4*)ap, *(const float4*)(ap + 4));
        acc[it] = __builtin_amdgcn_mfma_f32_16x16x32_bf16(wf, af, acc[it], 0, 0, 0);
      }
    }
  }

  if (MODE == 0) {
    float* out = (float*)outv;
#pragma unroll
    for (int nt = 0; nt < 4; ++nt) {
      float bn = bias[n0 + (nt << 4) + m16];
#pragma unroll
      for (int r = 0; r < 4; ++r) {
        int i = i0 + (wave << 4) + (quad << 2) + r;
        out[(size_t)i * 512 + n0 + (nt << 4) + m16] = acc[nt][r] + bn;
      }
    }
  } else if (MODE == 2) {
    ushort* out = (ushort*)outv;
    const int b = i0 >> 11, l0 = i0 & 2047, h = n0 >> 6;
#pragma unroll
    for (int nt = 0; nt < 4; ++nt) {
      float bn = bias[n0 + (nt << 4) + m16];
      int d = (nt << 4) + m16;
#pragma unroll
      for (int r = 0; r < 4; ++r) {
        int il = (wave << 4) + (quad << 2) + r;
        out[((size_t)(b * 8 + h) * 2048 + l0 + il) * 64 + d] = f2bf(acc[nt][r] + bn);
      }
    }
  } else {  // MODE 1: Vt [bh][d][l]
    ushort* out = (ushort*)outv;
    const int b = i0 >> 11, l0 = i0 & 2047, h = n0 >> 6;
    float4 b4 = *(const float4*)(bias + n0 + (wave << 4) + (quad << 2));
    float bb[4] = {b4.x, b4.y, b4.z, b4.w};
#pragma unroll
    for (int r = 0; r < 4; ++r) {
      int d = (wave << 4) + (quad << 2) + r;
#pragma unroll
      for (int it = 0; it < 4; ++it) {
        out[((size_t)(b * 8 + h) * 64 + d) * 2048 + l0 + (it << 4) + m16] =
            f2bf(acc[it][r] + bb[r]);
      }
    }
  }
}

template <int MODE>
__global__ __launch_bounds__(256) void gemm_mfma(const float* __restrict__ A,
                                                 const ushort* __restrict__ Wt,
                                                 const float* __restrict__ bias,
                                                 void* __restrict__ outv) {
  gemm_body<MODE>(A, Wt, bias, outv, blockIdx.x, blockIdx.y);
}

// Merged QKV projection: grid (8, 64, 3) -> 1536 blocks (6/CU) so the
// latency-bound fragment-from-global GEMMs can hide each other's stalls.
__global__ __launch_bounds__(256) void gemm_qkv(
    const float* __restrict__ q, const float* __restrict__ k,
    const float* __restrict__ v, const ushort* __restrict__ Wt,
    const float* __restrict__ bq, const float* __restrict__ bk,
    const float* __restrict__ bv, ushort* __restrict__ Qw,
    ushort* __restrict__ Kw, ushort* __restrict__ Vtw) {
  const int z = blockIdx.z;
  if (z == 0) {
    gemm_body<2>(q, Wt, bq, (void*)Qw, blockIdx.x, blockIdx.y);
  } else if (z == 1) {
    gemm_body<2>(k, Wt + 262144, bk, (void*)Kw, blockIdx.x, blockIdx.y);
  } else {
    gemm_body<1>(v, Wt + 2 * 262144, bv, (void*)Vtw, blockIdx.x, blockIdx.y);
  }
}

// ============================================================================
// qrel_mfma: qrel[bh][i][r] = sum_d Q[bh][i][d]*rel[r][d] (fp32 out, stride
// NREL_PAD). MFMA bf16, fragments direct from global. Grid (8, 32, 16).
// ============================================================================
__global__ __launch_bounds__(256) void qrel_mfma(const ushort* __restrict__ Qw,
                                                 const float* __restrict__ rel,
                                                 float* __restrict__ qrel) {
  const int t = threadIdx.x;
  const int lane = t & 63, wave = t >> 6;
  const int m16 = lane & 15, quad = lane >> 4;
  const int r0 = blockIdx.x * 64;
  const int i0 = blockIdx.y * 64;
  const int bh = blockIdx.z;
  const ushort* Qb = Qw + ((size_t)bh * 2048 + i0 + (wave << 4) + m16) * 64;
  bf16x8 qa0 = *(const bf16x8*)(Qb + (quad << 3));
  bf16x8 qa1 = *(const bf16x8*)(Qb + 32 + (quad << 3));

  f32x4 acc[4] = {{0.f, 0.f, 0.f, 0.f}, {0.f, 0.f, 0.f, 0.f},
                  {0.f, 0.f, 0.f, 0.f}, {0.f, 0.f, 0.f, 0.f}};
#pragma unroll
  for (int rt = 0; rt < 4; ++rt) {
    int rr = min(r0 + (rt << 4) + m16, NREL - 1);
    const float* rp = rel + (size_t)rr * 64 + (quad << 3);
    bf16x8 rf0 = pack8(*(const float4*)rp, *(const float4*)(rp + 4));
    bf16x8 rf1 = pack8(*(const float4*)(rp + 32), *(const float4*)(rp + 36));
    acc[rt] = __builtin_amdgcn_mfma_f32_16x16x32_bf16(qa0, rf0, acc[rt], 0, 0, 0);
    acc[rt] = __builtin_amdgcn_mfma_f32_16x16x32_bf16(qa1, rf1, acc[rt], 0, 0, 0);
  }
#pragma unroll
  for (int rt = 0; rt < 4; ++rt) {
    int r = r0 + (rt << 4) + m16;
    if (r < NREL_PAD) {
#pragma unroll
      for (int rg = 0; rg < 4; ++rg) {
        int i = i0 + (wave << 4) + (quad << 2) + rg;
        qrel[((size_t)bh * 2048 + i) * NREL_PAD + r] = acc[rt][rg];
      }
    }
  }
}

// ============================================================================
// Flash attention, MFMA bf16. Software-pipelined: K/V tile j+1 and the
// qrel/mask gathers for j+1 are issued as global->reg loads right after the
// staging barrier, so their latency hides under iteration j's compute.
// ============================================================================
__global__ __launch_bounds__(256) void flash_attn(
    const ushort* __restrict__ Qw, const ushort* __restrict__ Kw,
    const ushort* __restrict__ Vt, const float* __restrict__ qrel,
    const int* __restrict__ mask, float* __restrict__ attn) {
  __shared__ ushort QPs[64 * LDB];  // Q tile [i][d]; later P [i][j]
  __shared__ ushort Ks[64 * LDB];   // [j][d]
  __shared__ ushort Vs[64 * LDB];   // [d][j]
  const int t = threadIdx.x;
  const int lane = t & 63, wave = t >> 6;
  const int m16 = lane & 15, quad = lane >> 4;
  const int koff = quad << 3;
  const int i0 = blockIdx.x * 64;
  const int bh = blockIdx.y;
  const int b = bh >> 3, h = bh & 7;
  const ushort* Qb = Qw + (size_t)bh * 2048 * 64;
  const ushort* Kb = Kw + (size_t)bh * 2048 * 64;
  const ushort* Vb = Vt + (size_t)bh * 64 * 2048;
  const float* qrl = qrel + (size_t)bh * 2048 * NREL_PAD;
  const int* mb = mask + b * 2048;

  // staging slot for this thread (two uint4 per thread per buffer)
  const int row0 = t >> 3, off0 = (t & 7) << 3;
  const int row1 = (t + 256) >> 3, off1 = ((t + 256) & 7) << 3;

  // Q tile -> LDS
  *(uint4*)&QPs[row0 * LDB + off0] =
      *(const uint4*)(Qb + (size_t)(i0 + row0) * 64 + off0);
  *(uint4*)&QPs[row1 * LDB + off1] =
      *(const uint4*)(Qb + (size_t)(i0 + row1) * 64 + off1);
  __syncthreads();

  bf16x8 qa0 = *(const bf16x8*)&QPs[((wave << 4) + m16) * LDB + koff];
  bf16x8 qa1 = *(const bf16x8*)&QPs[((wave << 4) + m16) * LDB + 32 + koff];

  const int irow0 = i0 + (wave << 4) + (quad << 2);

  // ---- prologue prefetch for j0 = 0 ----
  uint4 kr0 = *(const uint4*)(Kb + (size_t)row0 * 64 + off0);
  uint4 kr1 = *(const uint4*)(Kb + (size_t)row1 * 64 + off1);
  uint4 vr0 = *(const uint4*)(Vb + (size_t)row0 * 2048 + off0);
  uint4 vr1 = *(const uint4*)(Vb + (size_t)row1 * 2048 + off1);
  float qv[4][4];
  int mk[4];
#pragma unroll
  for (int jt = 0; jt < 4; ++jt) {
    int j = (jt << 4) + m16;
    mk[jt] = mb[j];
#pragma unroll
    for (int r = 0; r < 4; ++r) {
      int i = irow0 + r;
      int rr = min(NREL - 1, max(0, j - i + (NREL / 2)));
      qv[jt][r] = qrl[(size_t)i * NREL_PAD + rr];
    }
  }

  float m_i[4], l_i[4];
  f32x4 oacc[4];
#pragma unroll
  for (int r = 0; r < 4; ++r) { m_i[r] = -INFINITY; l_i[r] = 0.f; }
#pragma unroll
  for (int dt = 0; dt < 4; ++dt) oacc[dt] = (f32x4){0.f, 0.f, 0.f, 0.f};

  for (int j0 = 0; j0 < 2048; j0 += 64) {
    __syncthreads();
    // stage prefetched K/V regs into LDS
    *(uint4*)&Ks[row0 * LDB + off0] = kr0;
    *(uint4*)&Ks[row1 * LDB + off1] = kr1;
    *(uint4*)&Vs[row0 * LDB + off0] = vr0;
    *(uint4*)&Vs[row1 * LDB + off1] = vr1;
    __syncthreads();

    // ---- issue next-tile prefetch (latency hides under this iter's compute)
    const int jn = (j0 + 64) & 2047;  // wraps to 0 on last iter (unused)
    uint4 kn0 = *(const uint4*)(Kb + (size_t)(jn + row0) * 64 + off0);
    uint4 kn1 = *(const uint4*)(Kb + (size_t)(jn + row1) * 64 + off1);
    uint4 vn0 = *(const uint4*)(Vb + (size_t)row0 * 2048 + jn + off0);
    uint4 vn1 = *(const uint4*)(Vb + (size_t)row1 * 2048 + jn + off1);
    float qn[4][4];
    int mkn[4];
#pragma unroll
    for (int jt = 0; jt < 4; ++jt) {
      int j = jn + (jt << 4) + m16;
      mkn[jt] = mb[j];
#pragma unroll
      for (int r = 0; r < 4; ++r) {
        int i = irow0 + r;
        int rr = min(NREL - 1, max(0, j - i + (NREL / 2)));
        qn[jt][r] = qrl[(size_t)i * NREL_PAD + rr];
      }
    }

    // ---- QK^T ----
    f32x4 sacc[4];
    __builtin_amdgcn_s_setprio(1);
#pragma unroll
    for (int jt = 0; jt < 4; ++jt) {
      bf16x8 kb0 = *(const bf16x8*)&Ks[((jt << 4) + m16) * LDB + koff];
      bf16x8 kb1 = *(const bf16x8*)&Ks[((jt << 4) + m16) * LDB + 32 + koff];
      f32x4 z = {0.f, 0.f, 0.f, 0.f};
      z = __builtin_amdgcn_mfma_f32_16x16x32_bf16(qa0, kb0, z, 0, 0, 0);
      z = __builtin_amdgcn_mfma_f32_16x16x32_bf16(qa1, kb1, z, 0, 0, 0);
      sacc[jt] = z;
    }
    __builtin_amdgcn_s_setprio(0);

    // ---- scores: scale + rel-bias (prefetched) + mask (prefetched) ----
    float sv[4][4];
#pragma unroll
    for (int jt = 0; jt < 4; ++jt) {
#pragma unroll
      for (int r = 0; r < 4; ++r) {
        float sc = sacc[jt][r] * 0.125f + qv[jt][r];
        sv[jt][r] = (mk[jt] == 0) ? -1e10f : sc;
      }
    }

    // ---- online softmax ----
    float al[4];
#pragma unroll
    for (int r = 0; r < 4; ++r) {
      float mx = fmaxf(fmaxf(sv[0][r], sv[1][r]), fmaxf(sv[2][r], sv[3][r]));
#pragma unroll
      for (int w = 1; w < 16; w <<= 1) mx = fmaxf(mx, __shfl_xor(mx, w, 16));
      float mnew = fmaxf(m_i[r], mx);
      al[r] = __expf(m_i[r] - mnew);
      float sum = 0.f;
#pragma unroll
      for (int jt = 0; jt < 4; ++jt) {
        float p = __expf(sv[jt][r] - mnew);
        sv[jt][r] = p;
        sum += p;
      }
#pragma unroll
      for (int w = 1; w < 16; w <<= 1) sum += __shfl_xor(sum, w, 16);
      m_i[r] = mnew;
      l_i[r] = l_i[r] * al[r] + sum;
#pragma unroll
      for (int dt = 0; dt < 4; ++dt) oacc[dt][r] *= al[r];
    }

    // ---- P -> LDS (per-wave region; intra-wave consume) ----
    const int prow0 = (wave << 4) + (quad << 2);
#pragma unroll
    for (int jt = 0; jt < 4; ++jt)
#pragma unroll
      for (int r = 0; r < 4; ++r)
        QPs[(prow0 + r) * LDB + (jt << 4) + m16] = f2bf(sv[jt][r]);
    __asm__ volatile("s_waitcnt lgkmcnt(0)" ::: "memory");

    bf16x8 pa0 = *(const bf16x8*)&QPs[((wave << 4) + m16) * LDB + koff];
    bf16x8 pa1 = *(const bf16x8*)&QPs[((wave << 4) + m16) * LDB + 32 + koff];
    __builtin_amdgcn_s_setprio(1);
#pragma unroll
    for (int dt = 0; dt < 4; ++dt) {
      bf16x8 vb0 = *(const bf16x8*)&Vs[((dt << 4) + m16) * LDB + koff];
      bf16x8 vb1 = *(const bf16x8*)&Vs[((dt << 4) + m16) * LDB + 32 + koff];
      oacc[dt] = __builtin_amdgcn_mfma_f32_16x16x32_bf16(pa0, vb0, oacc[dt], 0, 0, 0);
      oacc[dt] = __builtin_amdgcn_mfma_f32_16x16x32_bf16(pa1, vb1, oacc[dt], 0, 0, 0);
    }
    __builtin_amdgcn_s_setprio(0);

    // ---- rotate prefetched state ----
    kr0 = kn0; kr1 = kn1; vr0 = vn0; vr1 = vn1;
#pragma unroll
    for (int jt = 0; jt < 4; ++jt) {
      mk[jt] = mkn[jt];
#pragma unroll
      for (int r = 0; r < 4; ++r) qv[jt][r] = qn[jt][r];
    }
  }

#pragma unroll
  for (int r = 0; r < 4; ++r) {
    float inv = 1.0f / l_i[r];
    int i = irow0 + r;
    float* dst = attn + (size_t)(b * 2048 + i) * 512 + h * 64;
#pragma unroll
    for (int dt = 0; dt < 4; ++dt) dst[(dt << 4) + m16] = oacc[dt][r] * inv;
  }
}

// ============================================================================
extern "C" void kernel_launch(void* const* d_in, const int* in_sizes, int n_in,
                              void* d_out, int out_size, void* d_ws,
                              size_t ws_size, hipStream_t stream) {
  const float* query = (const float*)d_in[0];
  const float* key   = (const float*)d_in[1];
  const float* value = (const float*)d_in[2];
  const int*   mask  = (const int*)d_in[3];
  const float* Wq = (const float*)d_in[4];
  const float* bq = (const float*)d_in[5];
  const float* Wk = (const float*)d_in[6];
  const float* bk = (const float*)d_in[7];
  const float* Wv = (const float*)d_in[8];
  const float* bv = (const float*)d_in[9];
  const float* Wo = (const float*)d_in[10];
  const float* bo = (const float*)d_in[11];
  const float* rel = (const float*)d_in[12];

  char* w = (char*)d_ws;
  ushort* Qw  = (ushort*)w; w += (size_t)16 * 2048 * 64 * 2;       // 4 MB
  ushort* Kw  = (ushort*)w; w += (size_t)16 * 2048 * 64 * 2;       // 4 MB
  ushort* Vtw = (ushort*)w; w += (size_t)16 * 64 * 2048 * 2;       // 4 MB
  ushort* Wt  = (ushort*)w; w += (size_t)4 * 512 * 512 * 2;        // 2 MB
  float* qrel = (float*)w;  w += (size_t)16 * 2048 * NREL_PAD * 4; // 65.5 MB
  float* attn = (float*)w;                                         // 8 MB
  float* out = (float*)d_out;

  dim3 bb(256);
  hipLaunchKernelGGL(prep_wt, dim3(8, 8, 4), bb, 0, stream, Wq, Wk, Wv, Wo, Wt);
  hipLaunchKernelGGL(gemm_qkv, dim3(8, 64, 3), bb, 0, stream, query, key, value,
                     Wt, bq, bk, bv, Qw, Kw, Vtw);
  hipLaunchKernelGGL(qrel_mfma, dim3(8, 32, 16), bb, 0, stream, Qw, rel, qrel);
  hipLaunchKernelGGL(flash_attn, dim3(32, 16), bb, 0, stream, Qw, Kw, Vtw, qrel,
                     mask, attn);
  hipLaunchKernelGGL((gemm_mfma<0>), dim3(8, 64), bb, 0, stream, attn,
                     Wt + 3 * 262144, bo, (void*)out);
}